// Round 4
// baseline (115.953 us; speedup 1.0000x reference)
//
#include <hip/hip_runtime.h>
#include <hip/hip_bf16.h>

// Reference semantics (n=512, HIDDEN=128, GRID=32, POOL=8, N_CELLS=4):
//   ped j bins into a 32x32 subcell grid centred on ped i; last-write-wins
//   in ascending-j order == max-j wins; out-of-range j writes a ZERO vector
//   to cell 0 (can overwrite an in-range winner) -> winner enc 2j+1 / 2j,
//   atomicMax, parity selects contribution. pooled k = h*16 + g;
//   out = relu(pooled @ W + b).
// Restructured (r4): out[i] = relu(b + sum_{odd winners (j,g)} T[j][g][:])
// with T[j][g*128+o] = sum_h hidden[j][h] * W[h*16+g][o]  (dense GEMM,
// scatter-independent). Eliminates pooled/part round-trips + one kernel.
// ALL TENSORS FP32. ~81us of dur_us is two harness 256MiB ws-poison fills
// inside the timed window; controllable budget is the remaining ~19us.

#define N_PED 512
#define HID   128
#define OUTD  128
#define TCOLS 2048   // 16 cells * 128 outs

// ---------------- Kernel 1: T = hidden @ W  (re-indexed) ------------------
// grid (16 g, 16 mg); block 256 = 4 waves; wave wv handles rows wv*8..+8,
// lane o0 covers outputs {o0, o0+64} for coarse cell g. K=128 full.
__global__ __launch_bounds__(256) void gemm_T(
    const float* __restrict__ hidden,  // (512,128)
    const float* __restrict__ W,       // (2048,128) row = h*16+g
    float*       __restrict__ T)       // (512,2048) col = g*128+o
{
    const int g   = blockIdx.x;        // 0..15
    const int mg  = blockIdx.y;        // 0..15 -> rows mg*32..+32
    const int tid = threadIdx.x;

    __shared__ float hs[32 * 128];     // 16 KB A-tile
    const float* src = hidden + mg * 32 * HID;
    #pragma unroll
    for (int v = 0; v < 4; ++v) {
        const int off = v * 1024 + tid * 4;
        *(float4*)(hs + off) = *(const float4*)(src + off);
    }
    __syncthreads();

    const int o0 = tid & 63;
    const int wv = tid >> 6;           // 0..3
    const float* wbase = W + g * OUTD + o0;

    float acc[16];                     // [r][half]
    #pragma unroll
    for (int q = 0; q < 16; ++q) acc[q] = 0.f;

    for (int kk = 0; kk < 128; kk += 4) {
        float wl[8];                   // [q][half]
        #pragma unroll
        for (int q = 0; q < 4; ++q) {
            wl[q * 2 + 0] = wbase[(kk + q) * TCOLS];        // W[(k*16+g)*128+o0]
            wl[q * 2 + 1] = wbase[(kk + q) * TCOLS + 64];
        }
        #pragma unroll
        for (int r = 0; r < 8; ++r) {
            // wave-uniform LDS address -> broadcast b128, conflict-free
            const float4 a = *(const float4*)(hs + (wv * 8 + r) * 128 + kk);
            acc[r * 2 + 0] += a.x * wl[0] + a.y * wl[2] + a.z * wl[4] + a.w * wl[6];
            acc[r * 2 + 1] += a.x * wl[1] + a.y * wl[3] + a.z * wl[5] + a.w * wl[7];
        }
    }

    float* dst = T + g * OUTD + o0;
    #pragma unroll
    for (int r = 0; r < 8; ++r) {
        const int row = mg * 32 + wv * 8 + r;
        dst[row * TCOLS]      = acc[r * 2 + 0];
        dst[row * TCOLS + 64] = acc[r * 2 + 1];
    }
}

// ---------------- Kernel 2: winner scatter + compact + gather + epilogue --
// One block per ped i.
__global__ __launch_bounds__(256) void combine_kernel(
    const float* __restrict__ T,      // (512,2048)
    const float* __restrict__ obs2,   // (512,2)
    const float* __restrict__ bias,   // (128,)
    float*       __restrict__ out)    // (512,128)
{
    __shared__ int   winner[1024];
    __shared__ int   list[512];       // (j<<4)|g for odd (in-range) winners
    __shared__ int   lcnt;
    __shared__ float red[256];

    const int i   = blockIdx.x;
    const int tid = threadIdx.x;

    if (tid == 0) lcnt = 0;
    for (int c = tid; c < 1024; c += 256) winner[c] = -1;
    const float2 pi = ((const float2*)obs2)[i];
    __syncthreads();

    // Phase 1: scatter (2 j's per thread)
    for (int j = tid; j < N_PED; j += 256) {
        if (j == i) continue;
        const float2 pj = ((const float2*)obs2)[j];
        const float ox = (pj.x - pi.x) * 4.0f + 16.0f;  // /0.25 == *4 exact
        const float oy = (pj.y - pi.y) * 4.0f + 16.0f;
        const bool in = (ox >= 0.f) && (ox < 32.f) && (oy >= 0.f) && (oy < 32.f);
        int c, enc;
        if (in) { c = ((int)ox) * 32 + (int)oy; enc = 2 * j + 1; }
        else    { c = 0;                        enc = 2 * j;     }
        atomicMax(&winner[c], enc);
    }
    __syncthreads();

    // Phase 2: compact odd winners via wave ballot + prefix popcount.
    // NB: w=-1 has (w&1)==1 in two's complement -> must test w>0.
    const int lane = tid & 63;
    for (int r = 0; r < 4; ++r) {
        const int c = r * 256 + tid;
        const int w = winner[c];
        const bool take = (w > 0) && (w & 1);
        const unsigned long long m = __ballot(take);
        int base = 0;
        if (lane == 0 && m) base = atomicAdd(&lcnt, __popcll(m));
        base = __shfl(base, 0);
        if (take) {
            const int pre = __popcll(m & ((1ull << lane) - 1ull));
            const int gg  = ((c >> 8) & 3) * 4 + ((c >> 3) & 3); // (x>>3)*4+(y>>3)
            list[base + pre] = ((w >> 1) << 4) | gg;
        }
    }
    __syncthreads();

    // Phase 3: gather compacted T rows. o = tid&127 (coalesced 512B/row),
    // two halves split the list, LDS-reduce at the end.
    const int o    = tid & 127;
    const int half = tid >> 7;
    const int n    = lcnt;
    float acc = 0.f;
    for (int e = half; e < n; e += 2) {
        const int ent = list[e];
        acc += T[(ent >> 4) * TCOLS + (ent & 15) * OUTD + o];
    }
    red[tid] = acc;
    __syncthreads();
    if (tid < 128) {
        const float s = bias[tid] + red[tid] + red[tid + 128];
        out[i * OUTD + tid] = fmaxf(s, 0.f);
    }
}

extern "C" void kernel_launch(void* const* d_in, const int* in_sizes, int n_in,
                              void* d_out, int out_size, void* d_ws, size_t ws_size,
                              hipStream_t stream) {
    (void)in_sizes; (void)n_in; (void)out_size; (void)ws_size;
    const float* hidden = (const float*)d_in[0];  // (512,128)
    // d_in[1] = obs1, unused for type_='social'
    const float* obs2   = (const float*)d_in[2];  // (512,2)
    const float* W      = (const float*)d_in[3];  // (2048,128)
    const float* bias   = (const float*)d_in[4];  // (128,)

    float* T = (float*)d_ws;                      // 512*2048 f32 = 4 MB

    gemm_T<<<dim3(16, 16), dim3(256), 0, stream>>>(hidden, W, T);
    combine_kernel<<<dim3(N_PED), dim3(256), 0, stream>>>(T, obs2, bias,
                                                          (float*)d_out);
}

// Round 5
// 99.192 us; speedup vs baseline: 1.1690x; 1.1690x over previous
//
#include <hip/hip_runtime.h>
#include <hip/hip_bf16.h>

// Reference semantics (n=512, HIDDEN=128, GRID=32, POOL=8, N_CELLS=4):
//   ped j bins into a 32x32 subcell grid centred on ped i; last-write-wins
//   in ascending-j order == max-j wins; out-of-range j writes a ZERO vector
//   to cell 0 (can overwrite an in-range winner) -> winner enc 2j+1 / 2j,
//   LDS atomicMax, parity selects contribution. pooled k = h*16 + g;
//   out = relu(pooled @ W + b).  ALL TENSORS FP32.
// Structure = r3 (pool -> split-K gemm -> finish), which measured 100.6us.
// r4's T-factorization regressed (+15us: 1-wave/SIMD gemm_T latency +
// cross-XCD T gather) and is abandoned.
// r5 change: pool phase 2 compacts winners per coarse cell (LDS lists) so
// the gather loops ~19 entries instead of scanning 64 cells with branches.
// ~81us of dur_us is two harness 256MiB ws-poison fills in the timed window.

#define N_PED 512
#define HID   128
#define KDIM  2048   // HID * 16
#define OUTD  128

// ---------------- Kernel A: winner table + compact + pooled features ------
__global__ __launch_bounds__(256) void pool_kernel(
    const float* __restrict__ hidden,   // (512,128)
    const float* __restrict__ obs2,     // (512,2)
    float*       __restrict__ pooled)   // (512,2048) k = h*16 + g
{
    __shared__ int winner[1024];
    __shared__ int glist[16 * 64];      // per-coarse-cell winner j lists
    __shared__ int gcnt[16];

    const int i   = blockIdx.x;
    const int tid = threadIdx.x;

    for (int c = tid; c < 1024; c += 256) winner[c] = -1;
    if (tid < 16) gcnt[tid] = 0;
    const float2 pi = ((const float2*)obs2)[i];
    __syncthreads();

    // Phase 1: scatter winners (2 j's per thread).
    for (int j = tid; j < N_PED; j += 256) {
        if (j == i) continue;
        const float2 pj = ((const float2*)obs2)[j];
        const float ox = (pj.x - pi.x) * 4.0f + 16.0f;  // /0.25 == *4 exact
        const float oy = (pj.y - pi.y) * 4.0f + 16.0f;
        const bool in = (ox >= 0.f) && (ox < 32.f) && (oy >= 0.f) && (oy < 32.f);
        int c, enc;
        if (in) { c = ((int)ox) * 32 + (int)oy; enc = 2 * j + 1; }
        else    { c = 0;                        enc = 2 * j;     }
        atomicMax(&winner[c], enc);
    }
    __syncthreads();

    // Phase 2a: compact in-range winners per coarse cell.
    // NB: w=-1 has (w&1)==1 -> must test w>0. cell c = cx*32+cy;
    // coarse g = (cx>>3)*4 + (cy>>3) = ((c>>8)&3)*4 + ((c>>3)&3).
    #pragma unroll
    for (int r = 0; r < 4; ++r) {
        const int c = r * 256 + tid;
        const int w = winner[c];
        if (w > 0 && (w & 1)) {
            const int g   = ((c >> 8) & 3) * 4 + ((c >> 3) & 3);
            const int pos = atomicAdd(&gcnt[g], 1);
            glist[g * 64 + pos] = w >> 1;
        }
    }
    __syncthreads();

    // Phase 2b: gather. group g = tid>>4 (coarse cell), lane = tid&15 covers
    // 8 channels; 16 lanes span one hidden row (512B, 32B/lane). ~19 iters.
    const int g    = tid >> 4;
    const int lane = tid & 15;
    const int h0   = lane * 8;
    const int n    = gcnt[g];

    float acc[8] = {0.f,0.f,0.f,0.f,0.f,0.f,0.f,0.f};
    for (int e = 0; e < n; ++e) {
        const int j = glist[g * 64 + e];     // broadcast within group
        const float4 r0 = *(const float4*)(hidden + j * HID + h0);
        const float4 r1 = *(const float4*)(hidden + j * HID + h0 + 4);
        acc[0] += r0.x; acc[1] += r0.y; acc[2] += r0.z; acc[3] += r0.w;
        acc[4] += r1.x; acc[5] += r1.y; acc[6] += r1.z; acc[7] += r1.w;
    }

    float* dst = pooled + i * KDIM;
    #pragma unroll
    for (int q = 0; q < 8; ++q)
        dst[(h0 + q) * 16 + g] = acc[q];
}

// ---------------- Kernel B: split-K GEMM partials, 8 rows/block ----------
// grid (64 i-groups of 8, 4 k-chunks of 512); 256 thr: o = tid&127,
// half = tid>>7 covers 256 k. Partials: part[i][kc*2+half][o].
__global__ __launch_bounds__(256) void gemm_part(
    const float* __restrict__ pooled,  // (512,2048)
    const float* __restrict__ W,       // (2048,128)
    float*       __restrict__ part)    // (512,8,128)
{
    const int ig   = blockIdx.x;      // 0..63
    const int kc   = blockIdx.y;      // 0..3
    const int tid  = threadIdx.x;
    const int o    = tid & 127;
    const int half = tid >> 7;
    const int kbase = kc * 512 + half * 256;

    const float* p[8];
    #pragma unroll
    for (int r = 0; r < 8; ++r)
        p[r] = pooled + (ig * 8 + r) * KDIM + kbase;

    float acc[8] = {0.f,0.f,0.f,0.f,0.f,0.f,0.f,0.f};
    for (int kk = 0; kk < 256; kk += 4) {
        const int kb = (kbase + kk) * OUTD + o;
        const float w0 = W[kb];
        const float w1 = W[kb + OUTD];
        const float w2 = W[kb + 2 * OUTD];
        const float w3 = W[kb + 3 * OUTD];
        #pragma unroll
        for (int r = 0; r < 8; ++r) {
            const float4 a = *(const float4*)(p[r] + kk);
            acc[r] += a.x * w0 + a.y * w1 + a.z * w2 + a.w * w3;
        }
    }
    const int slot = kc * 2 + half;
    #pragma unroll
    for (int r = 0; r < 8; ++r)
        part[((ig * 8 + r) * 8 + slot) * OUTD + o] = acc[r];
}

// ---------------- Kernel C: reduce partials + bias + relu ----------------
__global__ __launch_bounds__(256) void finish_kernel(
    const float* __restrict__ part,   // (512,8,128)
    const float* __restrict__ bias,   // (128,)
    float*       __restrict__ out)    // (512,128)
{
    const int idx = blockIdx.x * 256 + threadIdx.x;  // 0..65535
    const int i = idx >> 7, o = idx & 127;
    float s = bias[o];
    #pragma unroll
    for (int m = 0; m < 8; ++m)
        s += part[(i * 8 + m) * OUTD + o];
    out[idx] = fmaxf(s, 0.0f);
}

extern "C" void kernel_launch(void* const* d_in, const int* in_sizes, int n_in,
                              void* d_out, int out_size, void* d_ws, size_t ws_size,
                              hipStream_t stream) {
    (void)in_sizes; (void)n_in; (void)out_size; (void)ws_size;
    const float* hidden = (const float*)d_in[0];  // (512,128)
    // d_in[1] = obs1, unused for type_='social'
    const float* obs2   = (const float*)d_in[2];  // (512,2)
    const float* W      = (const float*)d_in[3];  // (2048,128)
    const float* bias   = (const float*)d_in[4];  // (128,)

    float* pooled = (float*)d_ws;                    // 512*2048 f32 = 4 MB
    float* part   = pooled + (size_t)N_PED * KDIM;   // 512*8*128 f32 = 2 MB

    pool_kernel<<<dim3(N_PED), dim3(256), 0, stream>>>(hidden, obs2, pooled);
    gemm_part<<<dim3(64, 4), dim3(256), 0, stream>>>(pooled, W, part);
    finish_kernel<<<dim3(256), dim3(256), 0, stream>>>(part, bias, (float*)d_out);
}

// Round 6
// 97.979 us; speedup vs baseline: 1.1834x; 1.0124x over previous
//
#include <hip/hip_runtime.h>
#include <hip/hip_bf16.h>

// Reference semantics (n=512, HIDDEN=128, GRID=32, POOL=8, N_CELLS=4):
//   ped j bins into a 32x32 subcell grid centred on ped i; last-write-wins
//   in ascending-j order == max-j wins; out-of-range j writes a ZERO vector
//   to cell 0 (can overwrite an in-range winner) -> winner enc 2j+1 / 2j,
//   LDS atomicMax, parity selects contribution. pooled k = h*16 + g;
//   out = relu(pooled @ W + b).  ALL TENSORS FP32.
// History: r3 split-K=4 structure 100.6us; r4 T-factorization REGRESSED
// (+15us, latency-bound 1-wave/SIMD gemm + cross-XCD gather); r5 winner
// compaction 99.2us. ~81us of dur_us is two harness 256MiB ws-poison fills
// in the timed window — controllable budget ~18us.
// r6 change: split-K 4 -> 16 chunks (grid 256 -> 1024 blocks). W L2 traffic
// invariant to K-split; occupancy 1 -> 4 waves/SIMD hides the ~200cyc L2
// latency chain that dominates gemm_part.

#define N_PED 512
#define HID   128
#define KDIM  2048   // HID * 16
#define OUTD  128
#define NSLOT 32     // 16 k-chunks x 2 halves

// ---------------- Kernel A: winner table + compact + pooled features ------
__global__ __launch_bounds__(256) void pool_kernel(
    const float* __restrict__ hidden,   // (512,128)
    const float* __restrict__ obs2,     // (512,2)
    float*       __restrict__ pooled)   // (512,2048) k = h*16 + g
{
    __shared__ int winner[1024];
    __shared__ int glist[16 * 64];      // per-coarse-cell winner j lists
    __shared__ int gcnt[16];

    const int i   = blockIdx.x;
    const int tid = threadIdx.x;

    for (int c = tid; c < 1024; c += 256) winner[c] = -1;
    if (tid < 16) gcnt[tid] = 0;
    const float2 pi = ((const float2*)obs2)[i];
    __syncthreads();

    // Phase 1: scatter winners (2 j's per thread).
    for (int j = tid; j < N_PED; j += 256) {
        if (j == i) continue;
        const float2 pj = ((const float2*)obs2)[j];
        const float ox = (pj.x - pi.x) * 4.0f + 16.0f;  // /0.25 == *4 exact
        const float oy = (pj.y - pi.y) * 4.0f + 16.0f;
        const bool in = (ox >= 0.f) && (ox < 32.f) && (oy >= 0.f) && (oy < 32.f);
        int c, enc;
        if (in) { c = ((int)ox) * 32 + (int)oy; enc = 2 * j + 1; }
        else    { c = 0;                        enc = 2 * j;     }
        atomicMax(&winner[c], enc);
    }
    __syncthreads();

    // Phase 2a: compact in-range winners per coarse cell.
    // NB: w=-1 has (w&1)==1 -> must test w>0. cell c = cx*32+cy;
    // coarse g = (cx>>3)*4 + (cy>>3) = ((c>>8)&3)*4 + ((c>>3)&3).
    #pragma unroll
    for (int r = 0; r < 4; ++r) {
        const int c = r * 256 + tid;
        const int w = winner[c];
        if (w > 0 && (w & 1)) {
            const int g   = ((c >> 8) & 3) * 4 + ((c >> 3) & 3);
            const int pos = atomicAdd(&gcnt[g], 1);
            glist[g * 64 + pos] = w >> 1;
        }
    }
    __syncthreads();

    // Phase 2b: gather. group g = tid>>4, lane = tid&15 covers 8 channels;
    // 16 lanes span one hidden row (512B, 32B/lane). ~19 iters avg.
    const int g    = tid >> 4;
    const int lane = tid & 15;
    const int h0   = lane * 8;
    const int n    = gcnt[g];

    float acc[8] = {0.f,0.f,0.f,0.f,0.f,0.f,0.f,0.f};
    for (int e = 0; e < n; ++e) {
        const int j = glist[g * 64 + e];     // broadcast within group
        const float4 r0 = *(const float4*)(hidden + j * HID + h0);
        const float4 r1 = *(const float4*)(hidden + j * HID + h0 + 4);
        acc[0] += r0.x; acc[1] += r0.y; acc[2] += r0.z; acc[3] += r0.w;
        acc[4] += r1.x; acc[5] += r1.y; acc[6] += r1.z; acc[7] += r1.w;
    }

    float* dst = pooled + i * KDIM;
    #pragma unroll
    for (int q = 0; q < 8; ++q)
        dst[(h0 + q) * 16 + g] = acc[q];
}

// ---------------- Kernel B: split-K GEMM partials, 16 chunks -------------
// grid (64 i-groups of 8, 16 k-chunks of 128); 256 thr: o = tid&127,
// half = tid>>7 covers 64 k (16 iters). part[i][kc*2+half][o], 32 slots.
__global__ __launch_bounds__(256) void gemm_part(
    const float* __restrict__ pooled,  // (512,2048)
    const float* __restrict__ W,       // (2048,128)
    float*       __restrict__ part)    // (512,32,128)
{
    const int ig   = blockIdx.x;      // 0..63
    const int kc   = blockIdx.y;      // 0..15
    const int tid  = threadIdx.x;
    const int o    = tid & 127;
    const int half = tid >> 7;
    const int kbase = kc * 128 + half * 64;

    const float* p[8];
    #pragma unroll
    for (int r = 0; r < 8; ++r)
        p[r] = pooled + (ig * 8 + r) * KDIM + kbase;

    float acc[8] = {0.f,0.f,0.f,0.f,0.f,0.f,0.f,0.f};
    for (int kk = 0; kk < 64; kk += 4) {
        const int kb = (kbase + kk) * OUTD + o;
        const float w0 = W[kb];
        const float w1 = W[kb + OUTD];
        const float w2 = W[kb + 2 * OUTD];
        const float w3 = W[kb + 3 * OUTD];
        #pragma unroll
        for (int r = 0; r < 8; ++r) {
            const float4 a = *(const float4*)(p[r] + kk);
            acc[r] += a.x * w0 + a.y * w1 + a.z * w2 + a.w * w3;
        }
    }
    const int slot = kc * 2 + half;
    #pragma unroll
    for (int r = 0; r < 8; ++r)
        part[((ig * 8 + r) * NSLOT + slot) * OUTD + o] = acc[r];
}

// ---------------- Kernel C: reduce partials + bias + relu ----------------
__global__ __launch_bounds__(256) void finish_kernel(
    const float* __restrict__ part,   // (512,32,128)
    const float* __restrict__ bias,   // (128,)
    float*       __restrict__ out)    // (512,128)
{
    const int idx = blockIdx.x * 256 + threadIdx.x;  // 0..65535
    const int i = idx >> 7, o = idx & 127;
    float s = bias[o];
    #pragma unroll
    for (int m = 0; m < NSLOT; ++m)
        s += part[(i * NSLOT + m) * OUTD + o];
    out[idx] = fmaxf(s, 0.0f);
}

extern "C" void kernel_launch(void* const* d_in, const int* in_sizes, int n_in,
                              void* d_out, int out_size, void* d_ws, size_t ws_size,
                              hipStream_t stream) {
    (void)in_sizes; (void)n_in; (void)out_size; (void)ws_size;
    const float* hidden = (const float*)d_in[0];  // (512,128)
    // d_in[1] = obs1, unused for type_='social'
    const float* obs2   = (const float*)d_in[2];  // (512,2)
    const float* W      = (const float*)d_in[3];  // (2048,128)
    const float* bias   = (const float*)d_in[4];  // (128,)

    float* pooled = (float*)d_ws;                    // 512*2048 f32 = 4 MB
    float* part   = pooled + (size_t)N_PED * KDIM;   // 512*32*128 f32 = 8 MB

    pool_kernel<<<dim3(N_PED), dim3(256), 0, stream>>>(hidden, obs2, pooled);
    gemm_part<<<dim3(64, 16), dim3(256), 0, stream>>>(pooled, W, part);
    finish_kernel<<<dim3(256), dim3(256), 0, stream>>>(part, bias, (float*)d_out);
}

// Round 7
// 97.665 us; speedup vs baseline: 1.1873x; 1.0032x over previous
//
#include <hip/hip_runtime.h>
#include <hip/hip_bf16.h>

// Reference semantics (n=512, HIDDEN=128, GRID=32, POOL=8, N_CELLS=4):
//   ped j bins into a 32x32 subcell grid centred on ped i; last-write-wins
//   in ascending-j order == max-j wins; out-of-range j writes a ZERO vector
//   to cell 0 (can overwrite an in-range winner) -> winner enc 2j+1 / 2j,
//   LDS atomicMax, parity selects contribution. pooled k = h*16 + g;
//   out = relu(pooled @ W + b).  ALL TENSORS FP32.
// History: r3 100.6 (split-K=4, 8 rows); r4 T-factorization REGRESSED (+15);
// r5 99.2 (winner compaction); r6 98.0 (split-K=16, 4 waves/SIMD).
// ~81us of dur_us is two harness 256MiB ws-poison fills in the timed
// window — controllable budget ~17us.
// r7 change: gemm 8 -> 16 rows/block (grid 32x16=512 blocks, 2/CU).
// W L2 traffic = #i-groups x 1MB: 64MB -> 32MB; per-wave MLP doubles
// (20 indep VMEM / 64 FMA per k-step) to cover the 4->2 wave/SIMD drop.

#define N_PED 512
#define HID   128
#define KDIM  2048   // HID * 16
#define OUTD  128
#define NSLOT 32     // 16 k-chunks x 2 halves

// ---------------- Kernel A: winner table + compact + pooled features ------
__global__ __launch_bounds__(256) void pool_kernel(
    const float* __restrict__ hidden,   // (512,128)
    const float* __restrict__ obs2,     // (512,2)
    float*       __restrict__ pooled)   // (512,2048) k = h*16 + g
{
    __shared__ int winner[1024];
    __shared__ int glist[16 * 64];      // per-coarse-cell winner j lists
    __shared__ int gcnt[16];

    const int i   = blockIdx.x;
    const int tid = threadIdx.x;

    for (int c = tid; c < 1024; c += 256) winner[c] = -1;
    if (tid < 16) gcnt[tid] = 0;
    const float2 pi = ((const float2*)obs2)[i];
    __syncthreads();

    // Phase 1: scatter winners (2 j's per thread).
    for (int j = tid; j < N_PED; j += 256) {
        if (j == i) continue;
        const float2 pj = ((const float2*)obs2)[j];
        const float ox = (pj.x - pi.x) * 4.0f + 16.0f;  // /0.25 == *4 exact
        const float oy = (pj.y - pi.y) * 4.0f + 16.0f;
        const bool in = (ox >= 0.f) && (ox < 32.f) && (oy >= 0.f) && (oy < 32.f);
        int c, enc;
        if (in) { c = ((int)ox) * 32 + (int)oy; enc = 2 * j + 1; }
        else    { c = 0;                        enc = 2 * j;     }
        atomicMax(&winner[c], enc);
    }
    __syncthreads();

    // Phase 2a: compact in-range winners per coarse cell.
    // NB: w=-1 has (w&1)==1 -> must test w>0. cell c = cx*32+cy;
    // coarse g = (cx>>3)*4 + (cy>>3) = ((c>>8)&3)*4 + ((c>>3)&3).
    #pragma unroll
    for (int r = 0; r < 4; ++r) {
        const int c = r * 256 + tid;
        const int w = winner[c];
        if (w > 0 && (w & 1)) {
            const int g   = ((c >> 8) & 3) * 4 + ((c >> 3) & 3);
            const int pos = atomicAdd(&gcnt[g], 1);
            glist[g * 64 + pos] = w >> 1;
        }
    }
    __syncthreads();

    // Phase 2b: gather. group g = tid>>4, lane = tid&15 covers 8 channels;
    // 16 lanes span one hidden row (512B, 32B/lane). ~19 iters avg.
    const int g    = tid >> 4;
    const int lane = tid & 15;
    const int h0   = lane * 8;
    const int n    = gcnt[g];

    float acc[8] = {0.f,0.f,0.f,0.f,0.f,0.f,0.f,0.f};
    for (int e = 0; e < n; ++e) {
        const int j = glist[g * 64 + e];     // broadcast within group
        const float4 r0 = *(const float4*)(hidden + j * HID + h0);
        const float4 r1 = *(const float4*)(hidden + j * HID + h0 + 4);
        acc[0] += r0.x; acc[1] += r0.y; acc[2] += r0.z; acc[3] += r0.w;
        acc[4] += r1.x; acc[5] += r1.y; acc[6] += r1.z; acc[7] += r1.w;
    }

    float* dst = pooled + i * KDIM;
    #pragma unroll
    for (int q = 0; q < 8; ++q)
        dst[(h0 + q) * 16 + g] = acc[q];
}

// ---------------- Kernel B: split-K GEMM partials, 16 rows/block ---------
// grid (32 i-groups of 16, 16 k-chunks of 128); 256 thr: o = tid&127,
// half = tid>>7 covers 64 k. part[i][kc*2+half][o], 32 slots.
__global__ __launch_bounds__(256) void gemm_part(
    const float* __restrict__ pooled,  // (512,2048)
    const float* __restrict__ W,       // (2048,128)
    float*       __restrict__ part)    // (512,32,128)
{
    const int ig   = blockIdx.x;      // 0..31
    const int kc   = blockIdx.y;      // 0..15
    const int tid  = threadIdx.x;
    const int o    = tid & 127;
    const int half = tid >> 7;
    const int kbase = kc * 128 + half * 64;

    const float* pb = pooled + ig * 16 * KDIM + kbase;

    float acc[16];
    #pragma unroll
    for (int r = 0; r < 16; ++r) acc[r] = 0.f;

    for (int kk = 0; kk < 64; kk += 4) {
        const int kb = (kbase + kk) * OUTD + o;
        const float w0 = W[kb];
        const float w1 = W[kb + OUTD];
        const float w2 = W[kb + 2 * OUTD];
        const float w3 = W[kb + 3 * OUTD];
        #pragma unroll
        for (int r = 0; r < 16; ++r) {
            const float4 a = *(const float4*)(pb + r * KDIM + kk);
            acc[r] += a.x * w0 + a.y * w1 + a.z * w2 + a.w * w3;
        }
    }
    const int slot = kc * 2 + half;
    #pragma unroll
    for (int r = 0; r < 16; ++r)
        part[((ig * 16 + r) * NSLOT + slot) * OUTD + o] = acc[r];
}

// ---------------- Kernel C: reduce partials + bias + relu ----------------
__global__ __launch_bounds__(256) void finish_kernel(
    const float* __restrict__ part,   // (512,32,128)
    const float* __restrict__ bias,   // (128,)
    float*       __restrict__ out)    // (512,128)
{
    const int idx = blockIdx.x * 256 + threadIdx.x;  // 0..65535
    const int i = idx >> 7, o = idx & 127;
    float s = bias[o];
    #pragma unroll
    for (int m = 0; m < NSLOT; ++m)
        s += part[(i * NSLOT + m) * OUTD + o];
    out[idx] = fmaxf(s, 0.0f);
}

extern "C" void kernel_launch(void* const* d_in, const int* in_sizes, int n_in,
                              void* d_out, int out_size, void* d_ws, size_t ws_size,
                              hipStream_t stream) {
    (void)in_sizes; (void)n_in; (void)out_size; (void)ws_size;
    const float* hidden = (const float*)d_in[0];  // (512,128)
    // d_in[1] = obs1, unused for type_='social'
    const float* obs2   = (const float*)d_in[2];  // (512,2)
    const float* W      = (const float*)d_in[3];  // (2048,128)
    const float* bias   = (const float*)d_in[4];  // (128,)

    float* pooled = (float*)d_ws;                    // 512*2048 f32 = 4 MB
    float* part   = pooled + (size_t)N_PED * KDIM;   // 512*32*128 f32 = 8 MB

    pool_kernel<<<dim3(N_PED), dim3(256), 0, stream>>>(hidden, obs2, pooled);
    gemm_part<<<dim3(32, 16), dim3(256), 0, stream>>>(pooled, W, part);
    finish_kernel<<<dim3(256), dim3(256), 0, stream>>>(part, bias, (float*)d_out);
}